// Round 4
// baseline (539.879 us; speedup 1.0000x reference)
//
#include <hip/hip_runtime.h>
#include <hip/hip_bf16.h>
#include <stdint.h>

#define HCH 256
#define GEO 13
#define DEPTH 3
#define EPSBN 1e-5f
#define MFMA __builtin_amdgcn_mfma_f32_16x16x32_bf16

typedef __attribute__((ext_vector_type(8))) short short8;
typedef __attribute__((ext_vector_type(4))) float floatx4;

typedef __attribute__((address_space(1))) const void g_void;
typedef __attribute__((address_space(3))) void l_void;

// fp32 -> bf16 RNE
__device__ __forceinline__ short f2bs(float f) {
    unsigned u = __float_as_uint(f);
    unsigned r = (u + 0x7fffu + ((u >> 16) & 1u)) >> 16;
    return (short)r;
}

// ---------------- k_prep: weights->bf16 (transposed), node/geo->bf16, BN fold,
//                  output zeroing, branch compaction (cnt zeroed by memset before)
// W0t: [(br*25 + c)*256 + n]*32 + kk  (bf16), K padded 781->800
// Wht: [((br*3 + l)*8 + c)*256 + n]*32 + kk
// sc/of: (br*4 + layer)*256 + col   (layer 3 pre-multiplied by att[br])
// node_bf: [N][256] bf16 ; geo_bf: [E][32] bf16 zero-padded
__global__ void k_prep(const float* __restrict__ W0, const float* __restrict__ Wh,
                       const float* __restrict__ b0, const float* __restrict__ bh,
                       const float* __restrict__ gm, const float* __restrict__ bt,
                       const float* __restrict__ mn, const float* __restrict__ vr,
                       const float* __restrict__ att,
                       const float* __restrict__ node, const float* __restrict__ geo,
                       const int* __restrict__ edx_ij, const int* __restrict__ edx_jk,
                       const int* __restrict__ nei_p,
                       short* __restrict__ W0t, short* __restrict__ Wht,
                       float* __restrict__ sc, float* __restrict__ of,
                       short* __restrict__ node_bf, short* __restrict__ geo_bf,
                       int* __restrict__ lists, int* __restrict__ cnt,
                       float4* __restrict__ outz, int n4out,
                       int E, int d_in_dim, int nb_node, int nb_geo, int nb_out) {
    const int B_W0 = 100, B_WH = 96, B_SC = 16;
    __shared__ short s[32][256];
    int b = blockIdx.x, t = threadIdx.x;
    if (b < B_W0) {
        int c = b % 25, br = b / 25;
        #pragma unroll
        for (int kk = 0; kk < 32; ++kk) {
            int kidx = c * 32 + kk;
            float v = (kidx < d_in_dim) ? W0[((size_t)br * d_in_dim + kidx) * HCH + t] : 0.f;
            s[kk][t] = f2bs(v);   // coalesced global read (n fastest)
        }
        __syncthreads();
        size_t obase = ((size_t)(b) * 256 + t) * 32;
        #pragma unroll
        for (int g = 0; g < 4; ++g) {
            short8 v;
            #pragma unroll
            for (int j = 0; j < 8; ++j) v[j] = s[g * 8 + j][t];
            *reinterpret_cast<short8*>(W0t + obase + g * 8) = v;
        }
    } else if (b < B_W0 + B_WH) {
        int idx = b - B_W0;
        int c = idx & 7; idx >>= 3;
        int l = idx % 3, br = idx / 3;
        #pragma unroll
        for (int kk = 0; kk < 32; ++kk) {
            float v = Wh[((size_t)(br * DEPTH + l) * HCH + (c * 32 + kk)) * HCH + t];
            s[kk][t] = f2bs(v);
        }
        __syncthreads();
        size_t obase = ((size_t)(b - B_W0) * 256 + t) * 32;
        #pragma unroll
        for (int g = 0; g < 4; ++g) {
            short8 v;
            #pragma unroll
            for (int j = 0; j < 8; ++j) v[j] = s[g * 8 + j][t];
            *reinterpret_cast<short8*>(Wht + obase + g * 8) = v;
        }
    } else if (b < B_W0 + B_WH + B_SC) {
        int idx = (b - B_W0 - B_WH) * 256 + t; // 4096 elems
        int col = idx & 255, l = (idx >> 8) & 3, br = idx >> 10;
        int gi = (br * (DEPTH + 1) + l) * HCH + col;
        float sA = gm[gi] * rsqrtf(vr[gi] + EPSBN);
        float bias = (l == 0) ? b0[br * HCH + col] : bh[(br * DEPTH + (l - 1)) * HCH + col];
        float ofv = (bias - mn[gi]) * sA + bt[gi];
        if (l == 3) { float av = att[br]; sA *= av; ofv *= av; }  // fold att (relu out >=0)
        sc[idx] = sA;
        of[idx] = ofv;
    } else if (b < B_W0 + B_WH + B_SC + nb_node) {
        // node fp32 -> bf16, 8 elems/thread, coalesced
        size_t i = ((size_t)(b - B_W0 - B_WH - B_SC) * 256 + t) * 8;
        const float4* src = reinterpret_cast<const float4*>(node + i);
        float4 v0 = src[0], v1 = src[1];
        short8 pk;
        pk[0] = f2bs(v0.x); pk[1] = f2bs(v0.y); pk[2] = f2bs(v0.z); pk[3] = f2bs(v0.w);
        pk[4] = f2bs(v1.x); pk[5] = f2bs(v1.y); pk[6] = f2bs(v1.z); pk[7] = f2bs(v1.w);
        *reinterpret_cast<short8*>(node_bf + i) = pk;
    } else if (b < B_W0 + B_WH + B_SC + nb_node + nb_geo) {
        // geo [E][13] fp32 -> [E][32] bf16 zero-padded
        int i = (b - B_W0 - B_WH - B_SC - nb_node) * 256 + t;
        int e = i >> 2, cc = i & 3;
        if (e < E) {
            short8 pk;
            #pragma unroll
            for (int j = 0; j < 8; ++j) {
                int col = cc * 8 + j;
                pk[j] = (col < GEO) ? f2bs(geo[(size_t)e * GEO + col]) : (short)0;
            }
            *reinterpret_cast<short8*>(geo_bf + (size_t)e * 32 + cc * 8) = pk;
        }
    } else if (b < B_W0 + B_WH + B_SC + nb_node + nb_geo + nb_out) {
        // zero output (was k_zero)
        int i = (b - (B_W0 + B_WH + B_SC + nb_node + nb_geo)) * 256 + t;
        if (i < n4out) outz[i] = make_float4(0.f, 0.f, 0.f, 0.f);
    } else {
        // wave-aggregated branch compaction (4 atomics per wave)
        int e = (b - (B_W0 + B_WH + B_SC + nb_node + nb_geo + nb_out)) * 256 + t;
        int NEI = nei_p[0];
        int lane = t & 63;
        int br = -1;
        if (e < E)
            br = ((edx_ij[e] < NEI) ? 0 : 2) + ((edx_jk[e] < NEI) ? 0 : 1);
        unsigned long long lt = (lane == 63) ? 0x7fffffffffffffffull
                                             : ((1ull << lane) - 1ull);
        #pragma unroll
        for (int bb = 0; bb < 4; ++bb) {
            unsigned long long mk = __ballot(br == bb);
            if (mk) {
                int leader = __ffsll((long long)mk) - 1;
                int base = 0;
                if (lane == leader) base = atomicAdd(&cnt[bb], (int)__popcll(mk));
                base = __shfl(base, leader);
                if (br == bb) {
                    int pos = base + (int)__popcll(mk & lt);
                    lists[(size_t)bb * E + pos] = e;
                }
            }
        }
    }
}

// ---------------- k_main v5: 128-edge tile, 8 waves 2x4, wave tile 64x64 (acc[4][4])
// Arithmetic-intensity fix: per 64 edges per 8-chunk phase, LDS 128KB + B 64KB
// (v1: 256KB + 128KB; v4: 128KB + 256KB). v2's geometry, with the two causes of
// its spill-collapse removed: __launch_bounds__(512,2) -> 256-reg budget (acc 64 +
// ~70 live fits), and A dbuf'd in LDS via global_load_lds with issue-early /
// drain-late (staging latency hidden under the 8-chunk MFMA phase, unlike v3's
// back-to-back-barrier stall). Hidden layers ping-pong the two A buffers ->
// no WAR barrier before epilogue writes (7 barriers/block vs v1's 14).
// Swizzle scheme ((row&7)<<4 byte-XOR, pre-swizzled global source) verified in v3.
__global__ __launch_bounds__(512, 2)
void k_main(const short* __restrict__ node_bf, const short* __restrict__ geo_bf,
            const int* __restrict__ eidx,
            const short* __restrict__ W0t, const short* __restrict__ Wht,
            const float* __restrict__ sc, const float* __restrict__ of,
            const int* __restrict__ lists, const int* __restrict__ cnt,
            float* __restrict__ out, int E) {
    __shared__ __align__(16) short A0[128][256];   // 64 KB
    __shared__ __align__(16) short A1[128][256];   // 64 KB
    __shared__ __align__(16) short Ageo[128][40];  // 10 KB, 80 B row stride
    __shared__ int s_idx[3][128];
    __shared__ int s_e[128];

    int c0 = cnt[0], c1 = cnt[1], c2 = cnt[2], c3 = cnt[3];
    int t0 = (c0 + 127) >> 7, t1 = (c1 + 127) >> 7, t2 = (c2 + 127) >> 7, t3 = (c3 + 127) >> 7;
    int b = blockIdx.x;
    int br, tile, count;
    if (b < t0)                     { br = 0; tile = b;                count = c0; }
    else if (b < t0 + t1)           { br = 1; tile = b - t0;           count = c1; }
    else if (b < t0 + t1 + t2)      { br = 2; tile = b - t0 - t1;      count = c2; }
    else if (b < t0 + t1 + t2 + t3) { br = 3; tile = b - t0 - t1 - t2; count = c3; }
    else return;
    int m = count - tile * 128; if (m > 128) m = 128;

    int t = threadIdx.x;
    if (t < 128) {
        int e = (t < m) ? lists[(size_t)br * E + (size_t)tile * 128 + t] : 0;
        s_e[t] = (t < m) ? e : -1;
        s_idx[0][t] = eidx[e];
        s_idx[1][t] = eidx[E + e];
        s_idx[2][t] = eidx[2 * E + e];
    }
    __syncthreads();   // indices visible  [B0]

    int wvid = t >> 6, lane = t & 63, quad = lane >> 4, l16 = lane & 15;
    int wr = wvid >> 2, wc = wvid & 3;     // 2 row-groups x 4 col-groups
    int swz = (l16 & 7) << 4;              // row&7 == l16&7 for all A-read rows

    floatx4 acc[4][4];
    #pragma unroll
    for (int rt = 0; rt < 4; ++rt)
        #pragma unroll
        for (int ct = 0; ct < 4; ++ct)
            #pragma unroll
            for (int r = 0; r < 4; ++r) acc[rt][ct][r] = 0.f;

    int boff[4];
    #pragma unroll
    for (int ct = 0; ct < 4; ++ct)
        boff[ct] = (wc * 64 + ct * 16 + l16) * 32 + quad * 8;
    int aoff[4];
    #pragma unroll
    for (int rt = 0; rt < 4; ++rt)
        aoff[rt] = (wr * 64 + rt * 16 + l16) * 512;   // byte offset of A row

    short* Ag = &Ageo[0][0];

    // --- stage one 128-row node part into an A buffer via global_load_lds.
    // Wave wvid stages rows [wvid*16, wvid*16+16), 2 rows/instr (8 instr/wave).
    // Global source pre-swizzled; LDS dest linear (m173 pattern, verified in v3).
    auto stage_nodes = [&](short* Abuf, const int* idxp) {
        #pragma unroll
        for (int i = 0; i < 8; ++i) {
            int r0 = wvid * 16 + i * 2;
            int row = r0 + (lane >> 5);
            int e = idxp[row];
            int soff = ((lane & 31) * 16) ^ ((row & 7) << 4);
            const char* src = (const char*)(node_bf + (size_t)e * HCH) + soff;
            __builtin_amdgcn_global_load_lds((g_void*)src, (l_void*)(Abuf + r0 * 256),
                                             16, 0, 0);
        }
    };

    // --- 8-chunk gemm (K=256) from swizzled A buffer against a weight slab ---
    auto do_chunks8 = [&](const short* Abuf, const short* Wbase) {
        const char* Ab = (const char*)Abuf;
        #pragma unroll
        for (int c = 0; c < 8; ++c) {
            short8 af[4];
            #pragma unroll
            for (int rt = 0; rt < 4; ++rt)
                af[rt] = *reinterpret_cast<const short8*>(
                    Ab + aoff[rt] + ((c * 64 + quad * 16) ^ swz));
            #pragma unroll
            for (int ct = 0; ct < 4; ++ct) {
                short8 bc = *reinterpret_cast<const short8*>(
                    Wbase + (size_t)c * 8192 + boff[ct]);
                #pragma unroll
                for (int rt = 0; rt < 4; ++rt)
                    acc[rt][ct] = MFMA(af[rt], bc, acc[rt][ct], 0, 0, 0);
            }
        }
    };

    // --- BN+relu epilogue into target A buffer (swizzled bf16 writes) ---
    auto epilogue_to = [&](short* Abuf, int l) {
        char* Bw = (char*)Abuf;
        #pragma unroll
        for (int ct = 0; ct < 4; ++ct) {
            int col = wc * 64 + ct * 16 + l16;
            float sv = sc[(br * 4 + l) * HCH + col];
            float ov = of[(br * 4 + l) * HCH + col];
            int colb = col * 2;
            #pragma unroll
            for (int rt = 0; rt < 4; ++rt)
                #pragma unroll
                for (int r = 0; r < 4; ++r) {
                    int row = wr * 64 + rt * 16 + quad * 4 + r;
                    float h = fmaxf(acc[rt][ct][r] * sv + ov, 0.f);
                    *reinterpret_cast<short*>(
                        Bw + row * 512 + (colb ^ ((row & 7) << 4))) = f2bs(h);
                    acc[rt][ct][r] = 0.f;
                }
        }
    };

    // ---------------- layer 0: 3 node parts (i,j,k) + geo tail chunk ----------------
    // geo staged up front (plain store, covered by B1); part0 into A0.
    {
        int grow = t >> 2, gp = (t & 3) * 8;
        int ge = s_e[grow];
        short8 gv;
        if (ge >= 0) gv = *reinterpret_cast<const short8*>(geo_bf + (size_t)ge * 32 + gp);
        else {
            #pragma unroll
            for (int j = 0; j < 8; ++j) gv[j] = 0;
        }
        *reinterpret_cast<short8*>(Ag + grow * 40 + gp) = gv;
    }
    stage_nodes(&A0[0][0], s_idx[0]);
    __syncthreads();   // [B1] part0 + geo ready (vmcnt drained by barrier)

    // p=0: issue part1 -> A1, compute part0 from A0
    stage_nodes(&A1[0][0], s_idx[1]);
    do_chunks8(&A0[0][0], W0t + (size_t)(br * 25 + 0) * 8192);
    __syncthreads();   // [B2] part1 ready; A0 reads done

    // p=1: issue part2 -> A0 (WAR on A0 cleared by B2), compute part1 from A1
    stage_nodes(&A0[0][0], s_idx[2]);
    do_chunks8(&A1[0][0], W0t + (size_t)(br * 25 + 8) * 8192);
    __syncthreads();   // [B3] part2 ready; A1 reads done

    // p=2: compute part2 from A0, then geo tail chunk (Ageo)
    do_chunks8(&A0[0][0], W0t + (size_t)(br * 25 + 16) * 8192);
    {
        short8 afg[4];
        #pragma unroll
        for (int rt = 0; rt < 4; ++rt)
            afg[rt] = *reinterpret_cast<const short8*>(
                Ag + (wr * 64 + rt * 16 + l16) * 40 + quad * 8);
        const short* Wg = W0t + (size_t)(br * 25 + 24) * 8192;
        #pragma unroll
        for (int ct = 0; ct < 4; ++ct) {
            short8 bc = *reinterpret_cast<const short8*>(Wg + boff[ct]);
            #pragma unroll
            for (int rt = 0; rt < 4; ++rt)
                acc[rt][ct] = MFMA(afg[rt], bc, acc[rt][ct], 0, 0, 0);
        }
    }

    // layer0 epilogue -> A1 (no barrier needed: A1 reads all finished before B3)
    epilogue_to(&A1[0][0], 0);
    __syncthreads();   // [B4] h0 published in A1

    // ---------------- hidden layers ping-pong A1 -> A0 -> A1 ----------------
    do_chunks8(&A1[0][0], Wht + (size_t)((br * 3 + 0) * 8) * 8192);
    epilogue_to(&A0[0][0], 1);      // A0 reads finished before B4
    __syncthreads();   // [B5] h1 in A0

    do_chunks8(&A0[0][0], Wht + (size_t)((br * 3 + 1) * 8) * 8192);
    epilogue_to(&A1[0][0], 2);      // A1 reads finished before B5
    __syncthreads();   // [B6] h2 in A1

    do_chunks8(&A1[0][0], Wht + (size_t)((br * 3 + 2) * 8) * 8192);

    // final: relu (leaky+att folded into sc/of) -> scatter-add on node i
    #pragma unroll
    for (int ct = 0; ct < 4; ++ct) {
        int col = wc * 64 + ct * 16 + l16;
        float sv = sc[(br * 4 + 3) * HCH + col];
        float ov = of[(br * 4 + 3) * HCH + col];
        #pragma unroll
        for (int rt = 0; rt < 4; ++rt)
            #pragma unroll
            for (int r = 0; r < 4; ++r) {
                int row = wr * 64 + rt * 16 + quad * 4 + r;
                if (row < m) {
                    float h = fmaxf(acc[rt][ct][r] * sv + ov, 0.f);
                    atomicAdd(out + (size_t)s_idx[0][row] * HCH + col, h);
                }
            }
    }
}

// ---------------- host launcher ----------------
extern "C" void kernel_launch(void* const* d_in, const int* in_sizes, int n_in,
                              void* d_out, int out_size, void* d_ws, size_t ws_size,
                              hipStream_t stream) {
    const float* node  = (const float*)d_in[0];
    const float* geo   = (const float*)d_in[1];
    const int*   eidx  = (const int*)d_in[2];
    const int*   edxij = (const int*)d_in[3];
    const int*   edxjk = (const int*)d_in[4];
    const float* att   = (const float*)d_in[5];
    const float* W0    = (const float*)d_in[6];
    const float* b0    = (const float*)d_in[7];
    const float* Wh    = (const float*)d_in[8];
    const float* bh    = (const float*)d_in[9];
    const float* gm    = (const float*)d_in[10];
    const float* bt    = (const float*)d_in[11];
    const float* mn    = (const float*)d_in[12];
    const float* vr    = (const float*)d_in[13];
    const int*   neip  = (const int*)d_in[14];

    int E = in_sizes[3];
    int N = in_sizes[0] / HCH;
    int d_in_dim = in_sizes[6] / (4 * HCH);   // 781

    uint8_t* w = (uint8_t*)d_ws;
    size_t off = 0;
    short* W0t  = (short*)(w + off); off += (size_t)4 * 25 * 256 * 32 * 2;
    short* Wht  = (short*)(w + off); off += (size_t)4 * 3 * 8 * 256 * 32 * 2;
    float* sc   = (float*)(w + off); off += 4096 * 4;
    float* of   = (float*)(w + off); off += 4096 * 4;
    int*   lists= (int*)(w + off);   off += (size_t)4 * E * 4;
    int*   cnt  = (int*)(w + off);   off += 16;
    short* node_bf = (short*)(w + off); off += (size_t)N * HCH * 2;
    short* geo_bf  = (short*)(w + off); off += (size_t)E * 32 * 2;

    float* out = (float*)d_out;
    int n4 = out_size / 4;                    // out floats -> float4 count

    hipMemsetAsync(cnt, 0, 16, stream);       // branch counters

    int nb_node = N / 8;                      // N*256 elems / (256 thr * 8)
    int nb_geo  = (4 * E + 255) / 256;
    int nb_out  = (n4 + 255) / 256;
    int nb_cmp  = (E + 255) / 256;
    k_prep<<<100 + 96 + 16 + nb_node + nb_geo + nb_out + nb_cmp, 256, 0, stream>>>(
        W0, Wh, b0, bh, gm, bt, mn, vr, att, node, geo, edxij, edxjk, neip,
        W0t, Wht, sc, of, node_bf, geo_bf, lists, cnt,
        (float4*)out, n4, E, d_in_dim, nb_node, nb_geo, nb_out);

    int T = (E >> 7) + 8;
    k_main<<<T, 512, 0, stream>>>(node_bf, geo_bf, eidx, W0t, Wht,
                                  sc, of, lists, cnt, out, E);
}